// Round 6
// baseline (45.231 us; speedup 1.0000x reference)
//
#include <hip/hip_runtime.h>

#define DEGREE 32
#define DIMS 8
#define NB 32
#define NPOS 65536
#define BLOCK 256

// exp(-(x-c)^2/(2*0.04)) = exp2( K*(x-c)^2 ), K = -12.5*log2(e)
// u-substitution: u = x*SQK, cs = c*SQK with SQK = sqrt(-K) -> e = exp2(-(u-cs)^2)
#define SQK    4.24660911f            // sqrt(18.033688011112043)
#define CSTEPS (1.01f / 31.0f * 4.24660911f)

#define NCOMP 8192   // 32 batches * 256 blocks, 1 position per thread
#define NFILL 2048   // zero half: 4,194,304 float4 = 524,288 threads * 8

typedef __attribute__((ext_vector_type(2))) float f32x2;
typedef __attribute__((ext_vector_type(4))) float f32x4;

__global__ __launch_bounds__(BLOCK) void basis_kernel(
    const float* __restrict__ weights,    // (B, DIMS, DEGREE)
    const float* __restrict__ positions,  // (B, N)
    float* __restrict__ out,              // (B, N, DIMS)
    float* __restrict__ out_zero)         // (B, N, DIMS) -> zeros
{
    const int bid = blockIdx.x;
    const int tid = threadIdx.x;

    // ---- role split: every 5th block is a pure zero-filler ----
    if ((bid % 5) == 4) {
        const int f = bid / 5;                       // 0..NFILL-1
        f32x4* z = reinterpret_cast<f32x4*>(out_zero);
        const f32x4 zz = {0.0f, 0.0f, 0.0f, 0.0f};
        size_t idx = (size_t)f * BLOCK + tid;        // 0..524287
        #pragma unroll
        for (int k = 0; k < 8; ++k)
            __builtin_nontemporal_store(zz, &z[idx + (size_t)k * ((size_t)NFILL * BLOCK)]);
        return;
    }

    // ---- compute role ----
    const int cb = bid - bid / 5;                    // 0..NCOMP-1
    const int b  = cb >> 8;
    const int n  = ((cb & 255) << 8) + tid;

    const float* __restrict__ wb = weights + b * (DIMS * DEGREE);
    const float x = positions[(size_t)b * NPOS + n];
    const float u = x * SQK;

    f32x2 acc[DIMS];
    #pragma unroll
    for (int d = 0; d < DIMS; ++d) { acc[d].x = 0.0f; acc[d].y = 0.0f; }

    float c = 0.0f;                                  // running c_g * SQK
    #pragma unroll 4
    for (int gp = 0; gp < DEGREE / 2; ++gp) {
        const float d0 = u - c;
        const float d1 = d0 - CSTEPS;
        const float e0 = __builtin_amdgcn_exp2f(-(d0 * d0));  // neg = input modifier
        const float e1 = __builtin_amdgcn_exp2f(-(d1 * d1));
        f32x2 e2; e2.x = e0; e2.y = e1;
        const int g = gp * 2;
        #pragma unroll
        for (int d = 0; d < DIMS; ++d) {
            // adjacent g contiguous in memory; uniform addr -> s_load_dwordx2
            f32x2 w2 = *reinterpret_cast<const f32x2*>(wb + d * DEGREE + g);
            acc[d] = __builtin_elementwise_fma(e2, w2, acc[d]);  // v_pk_fma_f32
        }
        c += 2.0f * CSTEPS;
    }

    float r[DIMS];
    #pragma unroll
    for (int d = 0; d < DIMS; ++d) r[d] = acc[d].x + acc[d].y;

    const size_t base = ((size_t)b * NPOS + n) * DIMS;
    f32x4* o = reinterpret_cast<f32x4*>(out + base);
    const f32x4 r0 = {r[0], r[1], r[2], r[3]};
    const f32x4 r1 = {r[4], r[5], r[6], r[7]};
    __builtin_nontemporal_store(r0, &o[0]);
    __builtin_nontemporal_store(r1, &o[1]);
}

extern "C" void kernel_launch(void* const* d_in, const int* in_sizes, int n_in,
                              void* d_out, int out_size, void* d_ws, size_t ws_size,
                              hipStream_t stream) {
    const float* weights   = (const float*)d_in[0];
    // d_in[1] = weights_std: unused (second output is exactly zeros)
    const float* positions = (const float*)d_in[2];

    float* out      = (float*)d_out;
    float* out_zero = out + (size_t)NB * NPOS * DIMS;

    dim3 grid(NCOMP + NFILL);   // 10240 blocks, roles interleaved 4:1
    dim3 block(BLOCK);
    basis_kernel<<<grid, block, 0, stream>>>(weights, positions, out, out_zero);
}

// Round 7
// 37.639 us; speedup vs baseline: 1.2017x; 1.2017x over previous
//
#include <hip/hip_runtime.h>

#define DEGREE 32
#define DIMS 8
#define NB 32
#define NPOS 65536
#define BLOCK 256

// exp(-(x-c)^2/(2*0.04)) = exp2( K*(x-c)^2 ), K = -12.5*log2(e)
// u-substitution: u = x*SQK, cs = c*SQK with SQK = sqrt(-K) -> e = exp2(-(u-cs)^2)
#define SQK    4.24660911f            // sqrt(18.033688011112043)
#define CSTEPS (1.01f / 31.0f * 4.24660911f)

#define NFILLB 2048                   // fill kernel blocks: 2048*256*8 float4 = 67.1 MB
#define NCOMPB 8192                   // compute blocks: 32 batches * 256

typedef __attribute__((ext_vector_type(2))) float f32x2;
typedef __attribute__((ext_vector_type(4))) float f32x4;

// Pure streaming fill, shaped like rocclr fillBuffer (6.7 TB/s at ~10% occupancy).
__global__ __launch_bounds__(BLOCK) void zero_kernel(f32x4* __restrict__ z)
{
    const size_t idx = (size_t)blockIdx.x * BLOCK + threadIdx.x;   // 0..524287
    const f32x4 zz = {0.0f, 0.0f, 0.0f, 0.0f};
    #pragma unroll
    for (int k = 0; k < 8; ++k)
        z[idx + (size_t)k * ((size_t)NFILLB * BLOCK)] = zz;        // 1KB/wave/instr, contiguous
}

__global__ __launch_bounds__(BLOCK) void basis_kernel(
    const float* __restrict__ weights,    // (B, DIMS, DEGREE)
    const float* __restrict__ positions,  // (B, N)
    float* __restrict__ out)              // (B, N, DIMS)
{
    const int cb  = blockIdx.x;
    const int b   = cb >> 8;
    const int tid = threadIdx.x;
    const int n   = ((cb & 255) << 8) + tid;

    const float* __restrict__ wb = weights + b * (DIMS * DEGREE);
    const float x = positions[(size_t)b * NPOS + n];
    const float u = x * SQK;

    f32x2 acc[DIMS];
    #pragma unroll
    for (int d = 0; d < DIMS; ++d) { acc[d].x = 0.0f; acc[d].y = 0.0f; }

    float c = 0.0f;                                  // running c_g * SQK
    #pragma unroll 4
    for (int gp = 0; gp < DEGREE / 2; ++gp) {
        const float d0 = u - c;
        const float d1 = d0 - CSTEPS;
        const float e0 = __builtin_amdgcn_exp2f(-(d0 * d0));  // neg = input modifier
        const float e1 = __builtin_amdgcn_exp2f(-(d1 * d1));
        f32x2 e2; e2.x = e0; e2.y = e1;
        const int g = gp * 2;
        #pragma unroll
        for (int d = 0; d < DIMS; ++d) {
            // adjacent g contiguous in memory; uniform addr -> s_load_dwordx2
            f32x2 w2 = *reinterpret_cast<const f32x2*>(wb + d * DEGREE + g);
            acc[d] = __builtin_elementwise_fma(e2, w2, acc[d]);  // v_pk_fma_f32
        }
        c += 2.0f * CSTEPS;
    }

    float r[DIMS];
    #pragma unroll
    for (int d = 0; d < DIMS; ++d) r[d] = acc[d].x + acc[d].y;

    const size_t base = ((size_t)b * NPOS + n) * DIMS;
    f32x4* o = reinterpret_cast<f32x4*>(out + base);
    const f32x4 r0 = {r[0], r[1], r[2], r[3]};
    const f32x4 r1 = {r[4], r[5], r[6], r[7]};
    o[0] = r0;
    o[1] = r1;
}

extern "C" void kernel_launch(void* const* d_in, const int* in_sizes, int n_in,
                              void* d_out, int out_size, void* d_ws, size_t ws_size,
                              hipStream_t stream) {
    const float* weights   = (const float*)d_in[0];
    // d_in[1] = weights_std: unused (second output is exactly zeros)
    const float* positions = (const float*)d_in[2];

    float* out      = (float*)d_out;
    float* out_zero = out + (size_t)NB * NPOS * DIMS;

    zero_kernel<<<dim3(NFILLB), dim3(BLOCK), 0, stream>>>(
        reinterpret_cast<f32x4*>(out_zero));
    basis_kernel<<<dim3(NCOMPB), dim3(BLOCK), 0, stream>>>(weights, positions, out);
}

// Round 8
// 27.919 us; speedup vs baseline: 1.6201x; 1.3481x over previous
//
#include <hip/hip_runtime.h>

#define DEGREE 32
#define DIMS 8
#define NB 32
#define NPOS 65536
#define BLOCK 256

// e_g = exp2(K*(x - g*h)^2), K = -12.5*log2(e), h = 1.01/31.
// Geometric recurrence: s_{g+1}/s_g = q * r^(2g+1) with
//   q = 2^(-2Kh*x) = 2^(QCOEF*x),  r = 2^(K*h^2).
// Pairwise (S = (s_g, s_{g+1}), g even): S_{g+2} = S_g * M_g,
//   M_0 = (q^2*r^4, q^2*r^8),  M_{g+2} = M_g * r^8.
#define SQK    4.24660911f        // sqrt(-K): s_0 = exp2(-(x*SQK)^2)
#define QCOEF  1.17509838f        // -2*K*h
#define R1     0.9868193f         // r
#define R4     0.9483070f         // r^4
#define R8     0.8992862f         // r^8

#define NCOMP 8192   // 32 batches * 256 blocks, 1 position per thread
#define NFILL 2048   // zero half: 4,194,304 f32x4 = 524,288 threads * 8

typedef __attribute__((ext_vector_type(2))) float f32x2;
typedef __attribute__((ext_vector_type(4))) float f32x4;

__global__ __launch_bounds__(BLOCK) void basis_kernel(
    const float* __restrict__ weights,    // (B, DIMS, DEGREE)
    const float* __restrict__ positions,  // (B, N)
    float* __restrict__ out,              // (B, N, DIMS)
    float* __restrict__ out_zero)         // (B, N, DIMS) -> zeros
{
    const int bid = blockIdx.x;
    const int tid = threadIdx.x;

    // ---- role split: every 5th block is a pure zero-filler (dense stores) ----
    if ((bid % 5) == 4) {
        const int f = bid / 5;                       // 0..NFILL-1
        f32x4* z = reinterpret_cast<f32x4*>(out_zero);
        const f32x4 zz = {0.0f, 0.0f, 0.0f, 0.0f};
        size_t idx = (size_t)f * BLOCK + tid;        // 0..524287
        #pragma unroll
        for (int k = 0; k < 8; ++k)
            z[idx + (size_t)k * ((size_t)NFILL * BLOCK)] = zz;
        return;
    }

    // ---- compute role ----
    __shared__ float lds[BLOCK * DIMS];              // 8KB: block's output tile

    const int cb = bid - bid / 5;                    // 0..NCOMP-1
    const int b  = cb >> 8;
    const int n  = ((cb & 255) << 8) + tid;

    const float* __restrict__ wb = weights + b * (DIMS * DEGREE);
    const float x = positions[(size_t)b * NPOS + n];

    // recurrence state
    const float u  = x * SQK;
    const float s0 = __builtin_amdgcn_exp2f(-(u * u));   // e_0
    const float q  = __builtin_amdgcn_exp2f(QCOEF * x);
    const float q2 = q * q;
    f32x2 S; S.x = s0; S.y = s0 * q * R1;                // (e_0, e_1)
    f32x2 M; M.x = q2 * R4; M.y = q2 * R8;
    const f32x2 R8v = {R8, R8};

    f32x2 acc[DIMS];
    #pragma unroll
    for (int d = 0; d < DIMS; ++d) { acc[d].x = 0.0f; acc[d].y = 0.0f; }

    #pragma unroll 4
    for (int gp = 0; gp < DEGREE / 2; ++gp) {
        const f32x2 e2 = S;
        const int g = gp * 2;
        #pragma unroll
        for (int d = 0; d < DIMS; ++d) {
            // adjacent g contiguous in memory; uniform addr -> s_load_dwordx2
            f32x2 w2 = *reinterpret_cast<const f32x2*>(wb + d * DEGREE + g);
            acc[d] = __builtin_elementwise_fma(e2, w2, acc[d]);  // v_pk_fma_f32
        }
        S *= M;          // v_pk_mul_f32: advance (e_g, e_{g+1}) -> (e_{g+2}, e_{g+3})
        M *= R8v;        // v_pk_mul_f32: advance step ratio
    }

    // ---- dense store via LDS: position p's 8 floats at lds[8p] ----
    f32x4* lv = reinterpret_cast<f32x4*>(lds);
    {
        const f32x4 r0 = {acc[0].x + acc[0].y, acc[1].x + acc[1].y,
                          acc[2].x + acc[2].y, acc[3].x + acc[3].y};
        const f32x4 r1 = {acc[4].x + acc[4].y, acc[5].x + acc[5].y,
                          acc[6].x + acc[6].y, acc[7].x + acc[7].y};
        lv[tid * 2]     = r0;
        lv[tid * 2 + 1] = r1;
    }
    __syncthreads();

    // block's contiguous 8KB output region; wave stores are lane-dense 16B
    f32x4* oblk = reinterpret_cast<f32x4*>(out + ((size_t)b * NPOS + ((cb & 255) << 8)) * DIMS);
    oblk[tid]         = lv[tid];
    oblk[tid + BLOCK] = lv[tid + BLOCK];
}

extern "C" void kernel_launch(void* const* d_in, const int* in_sizes, int n_in,
                              void* d_out, int out_size, void* d_ws, size_t ws_size,
                              hipStream_t stream) {
    const float* weights   = (const float*)d_in[0];
    // d_in[1] = weights_std: unused (second output is exactly zeros)
    const float* positions = (const float*)d_in[2];

    float* out      = (float*)d_out;
    float* out_zero = out + (size_t)NB * NPOS * DIMS;

    dim3 grid(NCOMP + NFILL);   // 10240 blocks, roles interleaved 4:1
    dim3 block(BLOCK);
    basis_kernel<<<grid, block, 0, stream>>>(weights, positions, out, out_zero);
}

// Round 9
// 26.402 us; speedup vs baseline: 1.7132x; 1.0575x over previous
//
#include <hip/hip_runtime.h>

#define DEGREE 32
#define DIMS 8
#define NB 32
#define NPOS 65536
#define BLOCK 256

// e_g = exp2(K*(x - g*h)^2), K = -12.5*log2(e), h = 1.01/31.
// Geometric recurrence: s_{g+1}/s_g = q * r^(2g+1) with
//   q = 2^(-2Kh*x) = 2^(QCOEF*x),  r = 2^(K*h^2).
// Pairwise (S = (s_g, s_{g+1}), g even): S_{g+2} = S_g * M_g,
//   M_0 = (q^2*r^4, q^2*r^8),  M_{g+2} = M_g * r^8.
#define SQK    4.24660911f        // sqrt(-K): s_0 = exp2(-(x*SQK)^2)
#define QCOEF  1.17509838f        // -2*K*h
#define R1     0.9868193f         // r
#define R4     0.9483070f         // r^4
#define R8     0.8992862f         // r^8

#define NCOMP 8192   // 32 batches * 256 blocks, 1 position per thread

typedef __attribute__((ext_vector_type(2))) float f32x2;
typedef __attribute__((ext_vector_type(4))) float f32x4;

__global__ __launch_bounds__(BLOCK) void basis_kernel(
    const float* __restrict__ weights,    // (B, DIMS, DEGREE)
    const float* __restrict__ positions,  // (B, N)
    float* __restrict__ out,              // (B, N, DIMS)
    float* __restrict__ out_zero)         // (B, N, DIMS) -> zeros
{
    const int cb  = blockIdx.x;           // 0..NCOMP-1
    const int b   = cb >> 8;
    const int tid = threadIdx.x;
    const int n   = ((cb & 255) << 8) + tid;

    const float* __restrict__ wb = weights + b * (DIMS * DEGREE);
    const float x = positions[(size_t)b * NPOS + n];

    // ---- own zero tile (mirror offset): independent stores, drain under compute ----
    const size_t tileBase = ((size_t)b * NPOS + ((size_t)(cb & 255) << 8)) * DIMS;
    {
        f32x4* zblk = reinterpret_cast<f32x4*>(out_zero + tileBase);
        const f32x4 zz = {0.0f, 0.0f, 0.0f, 0.0f};
        zblk[tid]         = zz;
        zblk[tid + BLOCK] = zz;
    }

    // ---- recurrence state ----
    const float u  = x * SQK;
    const float s0 = __builtin_amdgcn_exp2f(-(u * u));   // e_0
    const float q  = __builtin_amdgcn_exp2f(QCOEF * x);
    const float q2 = q * q;
    f32x2 S; S.x = s0; S.y = s0 * q * R1;                // (e_0, e_1)
    f32x2 M; M.x = q2 * R4; M.y = q2 * R8;
    const f32x2 R8v = {R8, R8};

    f32x2 acc[DIMS];
    #pragma unroll
    for (int d = 0; d < DIMS; ++d) { acc[d].x = 0.0f; acc[d].y = 0.0f; }

    #pragma unroll 4
    for (int gp = 0; gp < DEGREE / 2; ++gp) {
        const f32x2 e2 = S;
        const int g = gp * 2;
        #pragma unroll
        for (int d = 0; d < DIMS; ++d) {
            // adjacent g contiguous in memory; uniform addr -> s_load_dwordx2
            f32x2 w2 = *reinterpret_cast<const f32x2*>(wb + d * DEGREE + g);
            acc[d] = __builtin_elementwise_fma(e2, w2, acc[d]);  // v_pk_fma_f32
        }
        S *= M;          // v_pk_mul_f32: advance (e_g, e_{g+1})
        M *= R8v;        // v_pk_mul_f32: advance step ratio
    }

    // ---- dense result store via LDS ----
    __shared__ float lds[BLOCK * DIMS];                  // 8KB
    f32x4* lv = reinterpret_cast<f32x4*>(lds);
    {
        const f32x4 r0 = {acc[0].x + acc[0].y, acc[1].x + acc[1].y,
                          acc[2].x + acc[2].y, acc[3].x + acc[3].y};
        const f32x4 r1 = {acc[4].x + acc[4].y, acc[5].x + acc[5].y,
                          acc[6].x + acc[6].y, acc[7].x + acc[7].y};
        lv[tid * 2]     = r0;
        lv[tid * 2 + 1] = r1;
    }
    __syncthreads();

    f32x4* oblk = reinterpret_cast<f32x4*>(out + tileBase);
    oblk[tid]         = lv[tid];
    oblk[tid + BLOCK] = lv[tid + BLOCK];
}

extern "C" void kernel_launch(void* const* d_in, const int* in_sizes, int n_in,
                              void* d_out, int out_size, void* d_ws, size_t ws_size,
                              hipStream_t stream) {
    const float* weights   = (const float*)d_in[0];
    // d_in[1] = weights_std: unused (second output is exactly zeros)
    const float* positions = (const float*)d_in[2];

    float* out      = (float*)d_out;
    float* out_zero = out + (size_t)NB * NPOS * DIMS;

    dim3 grid(NCOMP);
    dim3 block(BLOCK);
    basis_kernel<<<grid, block, 0, stream>>>(weights, positions, out, out_zero);
}